// Round 12
// baseline (762.369 us; speedup 1.0000x reference)
//
#include <hip/hip_runtime.h>
#include <math.h>

#define N_NODES 100000
#define N_EDGES 1600000
#define NCLS 40
#define BN_EPS 1e-5f

// ---- bucketed CSR build parameters ----
#define BSPAN 256
#define NBKT 391
#define GBIN 256
#define CHUNK (N_EDGES / GBIN)
#define ECAP 5120

typedef unsigned int u32;
typedef unsigned short u16;
typedef __attribute__((ext_vector_type(8))) short bf16x8;
typedef __attribute__((ext_vector_type(4))) float f32x4;

__device__ inline float bl_lo(u32 u) { u32 x = u << 16; return __builtin_bit_cast(float, x); }
__device__ inline float bl_hi(u32 u) { u32 x = u & 0xFFFF0000u; return __builtin_bit_cast(float, x); }
__device__ inline u16 f2bl(float f) {  // RNE
    u32 x = __builtin_bit_cast(u32, f);
    return (u16)((x + 0x7FFFu + ((x >> 16) & 1u)) >> 16);
}
__device__ inline u32 pk2(float lo, float hi) { return (u32)f2bl(lo) | ((u32)f2bl(hi) << 16); }

// ---------------- Phase A: per-WG bucket binning (packed u32 pairs) ----------------
__global__ __launch_bounds__(256) void binA_kernel(const int* __restrict__ ei,
                                                   u32* __restrict__ ebuf,
                                                   int* __restrict__ runstart) {
    __shared__ int hist[NBKT];
    __shared__ int tmp[256];
    const int s = blockIdx.x, tid = threadIdx.x;
    const int e0 = s * CHUNK;

    for (int b = tid; b < NBKT; b += 256) hist[b] = 0;
    __syncthreads();
    for (int j = tid; j < CHUNK; j += 256) {
        int dst = ei[N_EDGES + e0 + j];
        atomicAdd(&hist[dst >> 8], 1);
    }
    __syncthreads();
    int i0 = 2 * tid, i1 = 2 * tid + 1;
    int a = (i0 < NBKT) ? hist[i0] : 0;
    int c = (i1 < NBKT) ? hist[i1] : 0;
    int ps = a + c;
    tmp[tid] = ps;
    __syncthreads();
    for (int o = 1; o < 256; o <<= 1) {
        int t = (tid >= o) ? tmp[tid - o] : 0;
        __syncthreads();
        tmp[tid] += t;
        __syncthreads();
    }
    int excl = tmp[tid] - ps;
    if (i0 < NBKT) hist[i0] = excl;
    if (i1 < NBKT) hist[i1] = excl + a;
    __syncthreads();
    for (int b = tid; b < NBKT; b += 256) runstart[b * GBIN + s] = hist[b];
    if (tid == 0) runstart[NBKT * GBIN + s] = CHUNK;
    __syncthreads();
    for (int j = tid; j < CHUNK; j += 256) {
        int src = ei[e0 + j];
        int dst = ei[N_EDGES + e0 + j];
        int p = atomicAdd(&hist[dst >> 8], 1);
        ebuf[e0 + p] = (u32)src | ((u32)(dst & 255) << 17);
    }
}

// ---------------- Phase C: per-bucket counting sort in LDS ----------------
__global__ __launch_bounds__(256) void binC_kernel(const u32* __restrict__ ebuf,
                                                   const int* __restrict__ runstart,
                                                   int* __restrict__ csr, int* __restrict__ offs,
                                                   float* __restrict__ dinv) {
    __shared__ int srcs[ECAP];
    __shared__ unsigned char dl8[ECAP];
    __shared__ int sorted[ECAP + BSPAN];
    __shared__ int nodecnt[BSPAN];
    __shared__ int cursor[BSPAN];
    __shared__ int tmp[256];
    __shared__ int sbase;
    const int b = blockIdx.x, tid = threadIdx.x;
    const int nb0 = b * BSPAN;
    const int nnod = min(BSPAN, N_NODES - nb0);

    int r0 = runstart[b * GBIN + tid];
    int r1 = runstart[(b + 1) * GBIN + tid];
    int len = r1 - r0;

    tmp[tid] = r0;
    __syncthreads();
    for (int o = 128; o >= 1; o >>= 1) {
        if (tid < o) tmp[tid] += tmp[tid + o];
        __syncthreads();
    }
    if (tid == 0) sbase = tmp[0] + nb0;
    __syncthreads();
    const int base = sbase;

    tmp[tid] = len;
    __syncthreads();
    for (int o = 1; o < 256; o <<= 1) {
        int t = (tid >= o) ? tmp[tid - o] : 0;
        __syncthreads();
        tmp[tid] += t;
        __syncthreads();
    }
    int myoff = tmp[tid] - len;
    int total_e = tmp[255];
    if (total_e > ECAP) total_e = ECAP;
    for (int n = tid; n < BSPAN; n += 256) nodecnt[n] = 0;
    __syncthreads();
    const u32* seg = ebuf + (size_t)tid * CHUNK + r0;
    for (int j = 0; j < len; ++j) {
        int idx = myoff + j;
        if (idx >= ECAP) break;
        u32 p = seg[j];
        srcs[idx] = (int)(p & 0x1FFFFu);
        int dl = (int)(p >> 17);
        dl8[idx] = (unsigned char)dl;
        atomicAdd(&nodecnt[dl], 1);
    }
    __syncthreads();
    int cnt = (tid < nnod) ? (nodecnt[tid] + 1) : 0;
    tmp[tid] = cnt;
    __syncthreads();
    for (int o = 1; o < 256; o <<= 1) {
        int t = (tid >= o) ? tmp[tid - o] : 0;
        __syncthreads();
        tmp[tid] += t;
        __syncthreads();
    }
    int noff = tmp[tid] - cnt;
    if (tid < nnod) {
        cursor[tid] = noff + 1;
        sorted[noff] = nb0 + tid;
        offs[nb0 + tid] = base + noff;
        dinv[nb0 + tid] = rsqrtf((float)(nodecnt[tid] + 1));
    }
    if (b == NBKT - 1 && tid == 0) offs[N_NODES] = N_EDGES + N_NODES;
    __syncthreads();
    for (int idx = tid; idx < total_e; idx += 256) {
        int dl = dl8[idx];
        int p = atomicAdd(&cursor[dl], 1);
        sorted[p] = srcs[idx];
    }
    __syncthreads();
    int tot = total_e + nnod;
    for (int idx = tid; idx < tot; idx += 256) csr[base + idx] = sorted[idx];
}

// ---------------- W prep: transpose + bf16 (+ stats zeroing in block 3) ----------------
__global__ void prep_w(const float* __restrict__ W1, const float* __restrict__ W2,
                       const float* __restrict__ W3, u16* __restrict__ Wt1,
                       u16* __restrict__ Wt2, u16* __restrict__ Wt3,
                       float* __restrict__ stats1, float* __restrict__ stats2) {
    int b = blockIdx.x, t = threadIdx.x;
    if (b == 0) {
        for (int idx = t; idx < 128 * 128; idx += 256) {
            int c = idx >> 7, k = idx & 127;
            Wt1[idx] = f2bl(W1[k * 128 + c]);
        }
    } else if (b == 1) {
        for (int idx = t; idx < 128 * 128; idx += 256) {
            int c = idx >> 7, k = idx & 127;
            Wt2[idx] = f2bl(W2[k * 128 + c]);
        }
    } else if (b == 2) {
        for (int idx = t; idx < 48 * 128; idx += 256) {
            int c = idx >> 7, k = idx & 127;
            Wt3[idx] = (c < NCLS) ? f2bl(W3[k * NCLS + c]) : (u16)0;
        }
    } else {
        stats1[t] = 0.f;
        stats2[t] = 0.f;
    }
}

// ---------------- MFMA GEMM: Y = dinv[row] * (fold(X[M x 128]) @ W[128 x BN]) ----------------
// Sliced bf16 layout for 128-wide buffers: [2 slices][N][64 feats] (slice = f>>6)
template <bool FOLD, bool IN_BF16, int BN, int OUTMODE>
__global__ __launch_bounds__(256) void mfma_gemm(const void* __restrict__ Xv,
                                                 const u16* __restrict__ Wt,
                                                 const float* __restrict__ ac,
                                                 const float* __restrict__ dinv,
                                                 void* __restrict__ Yv) {
    __shared__ __align__(16) u16 sX[64 * 128];
    __shared__ __align__(16) u16 sW[BN * 128];
    const int tid = threadIdx.x;
    const int row0 = blockIdx.x * 64;

    for (int ci = tid; ci < BN * 16; ci += 256) {
        int n = ci >> 4, ch = ci & 15;
        uint4 v = *(const uint4*)(Wt + n * 128 + ch * 8);
        *(uint4*)&sW[n * 128 + ((ch ^ (n & 7)) * 8)] = v;
    }
    {
        int r = tid >> 2;
        int gr = row0 + r;
        if (gr >= N_NODES) gr = N_NODES - 1;
        #pragma unroll
        for (int i = 0; i < 4; ++i) {
            int ch = (tid & 3) * 4 + i;
            int k0 = ch * 8;
            float xv[8];
            if (IN_BF16) {
                // sliced [2][N][64]: feats ch*8..ch*8+7 -> slice ch>>3, offset (ch&7)*8
                uint4 v = *(const uint4*)((const u16*)Xv +
                                          ((size_t)(ch >> 3) * N_NODES + gr) * 64 + (ch & 7) * 8);
                xv[0] = bl_lo(v.x); xv[1] = bl_hi(v.x);
                xv[2] = bl_lo(v.y); xv[3] = bl_hi(v.y);
                xv[4] = bl_lo(v.z); xv[5] = bl_hi(v.z);
                xv[6] = bl_lo(v.w); xv[7] = bl_hi(v.w);
            } else {
                float4 p = *((const float4*)Xv + (size_t)gr * 32 + ch * 2);
                float4 q = *((const float4*)Xv + (size_t)gr * 32 + ch * 2 + 1);
                xv[0] = p.x; xv[1] = p.y; xv[2] = p.z; xv[3] = p.w;
                xv[4] = q.x; xv[5] = q.y; xv[6] = q.z; xv[7] = q.w;
            }
            if (FOLD) {
                #pragma unroll
                for (int j = 0; j < 8; ++j)
                    xv[j] = fmaxf(fmaf(xv[j], ac[k0 + j], ac[128 + k0 + j]), 0.f);
            }
            uint4 w;
            w.x = pk2(xv[0], xv[1]); w.y = pk2(xv[2], xv[3]);
            w.z = pk2(xv[4], xv[5]); w.w = pk2(xv[6], xv[7]);
            *(uint4*)&sX[r * 128 + ((ch ^ (r & 7)) * 8)] = w;
        }
    }
    __syncthreads();

    const int w = tid >> 6, l = tid & 63;
    const int g = l >> 4;
    const int lrow = w * 16 + (l & 15);
    bf16x8 afrag[4];
    #pragma unroll
    for (int kc = 0; kc < 4; ++kc) {
        int ch = kc * 4 + g;
        afrag[kc] = *(const bf16x8*)&sX[lrow * 128 + ((ch ^ (lrow & 7)) * 8)];
    }
    float sc[4];
    #pragma unroll
    for (int r = 0; r < 4; ++r) {
        int row = row0 + w * 16 + g * 4 + r;
        sc[r] = (row < N_NODES) ? dinv[row] : 0.f;
    }
    #pragma unroll
    for (int cg = 0; cg < BN / 16; ++cg) {
        const int n = cg * 16 + (l & 15);
        f32x4 acc = {0.f, 0.f, 0.f, 0.f};
        #pragma unroll
        for (int kc = 0; kc < 4; ++kc) {
            int ch = kc * 4 + g;
            bf16x8 bfrag = *(const bf16x8*)&sW[n * 128 + ((ch ^ (n & 7)) * 8)];
            acc = __builtin_amdgcn_mfma_f32_16x16x32_bf16(afrag[kc], bfrag, acc, 0, 0, 0);
        }
        #pragma unroll
        for (int r = 0; r < 4; ++r) {
            int row = row0 + w * 16 + g * 4 + r;
            if (row < N_NODES) {
                if (OUTMODE == 0) {
                    // sliced store: slice n>>6, within-slice feat n&63
                    ((u16*)Yv)[((size_t)(n >> 6) * N_NODES + row) * 64 + (n & 63)] =
                        f2bl(acc[r] * sc[r]);
                } else {
                    if (n < NCLS) ((u16*)Yv)[(size_t)row * NCLS + n] = f2bl(acc[r] * sc[r]);
                }
            }
        }
    }
}

// ---------------- aggregation v3: 2-slice [2][N][64], XCD-parity-local ----------------
// grid = 2*N; slice = blockIdx & 1 (even XCDs -> slice 0, odd -> slice 1); wave = 1 node.
// lane = eg*8 + c : eg = edge slot (0..7), c = 16B chunk of the 128B slice row.
// 8 edges per gather instruction round; exec-masked tail (no redundant requests).
__global__ __launch_bounds__(64) void agg_kernel(const u32* __restrict__ hin,
                                                 const float* __restrict__ dinv,
                                                 const int* __restrict__ offs,
                                                 const int* __restrict__ csr,
                                                 const float* __restrict__ bias,
                                                 u32* __restrict__ hout) {
    const int sl = blockIdx.x & 1;
    const int i = blockIdx.x >> 1;
    const int l = threadIdx.x;
    const int eg = l >> 3, c = l & 7;
    const uint4* hs = (const uint4*)(hin + (size_t)sl * N_NODES * 32);
    uint4* os = (uint4*)(hout + (size_t)sl * N_NODES * 32);
    const int e0 = offs[i], e1 = offs[i + 1];
    float a[8] = {};
    for (int e = e0; e < e1; e += 8) {
        int ej = e + eg;
        if (ej < e1) {
            int s = csr[ej];
            uint4 u = hs[(size_t)s * 8 + c];
            a[0] += bl_lo(u.x); a[1] += bl_hi(u.x);
            a[2] += bl_lo(u.y); a[3] += bl_hi(u.y);
            a[4] += bl_lo(u.z); a[5] += bl_hi(u.z);
            a[6] += bl_lo(u.w); a[7] += bl_hi(u.w);
        }
    }
    #pragma unroll
    for (int j = 0; j < 8; ++j) {
        a[j] += __shfl_xor(a[j], 8);
        a[j] += __shfl_xor(a[j], 16);
        a[j] += __shfl_xor(a[j], 32);
    }
    if (l < 8) {
        const float di = dinv[i];
        float4 b0 = *(const float4*)(bias + sl * 64 + c * 8);
        float4 b1 = *(const float4*)(bias + sl * 64 + c * 8 + 4);
        uint4 o;
        o.x = pk2(fmaf(a[0], di, b0.x), fmaf(a[1], di, b0.y));
        o.y = pk2(fmaf(a[2], di, b0.z), fmaf(a[3], di, b0.w));
        o.z = pk2(fmaf(a[4], di, b1.x), fmaf(a[5], di, b1.y));
        o.w = pk2(fmaf(a[6], di, b1.z), fmaf(a[7], di, b1.w));
        os[(size_t)i * 8 + c] = o;
    }
}

// ---------------- BN statistics: [2][N][64] sliced layout ----------------
// 512 x 256 = 2048 waves; wave -> slice (wg&1), row stripe; lane = nd*8 + c.
__global__ __launch_bounds__(256) void stats_kernel(const u32* __restrict__ h,
                                                    float* __restrict__ stats) {
    const int tid = threadIdx.x;
    const int lane = tid & 63, wv = tid >> 6;
    const int wg = blockIdx.x * 4 + wv;
    const int sl = wg & 1;
    const int wr = wg >> 1;                    // 0..1023
    const int nd = lane >> 3, c = lane & 7;
    const uint4* hs = (const uint4*)(h + (size_t)sl * N_NODES * 32);
    float s[8] = {}, q[8] = {};
    for (int r0 = wr * 8; r0 < N_NODES; r0 += 8192) {
        int row = r0 + nd;
        if (row < N_NODES) {
            uint4 u = hs[(size_t)row * 8 + c];
            float f;
            f = bl_lo(u.x); s[0] += f; q[0] = fmaf(f, f, q[0]);
            f = bl_hi(u.x); s[1] += f; q[1] = fmaf(f, f, q[1]);
            f = bl_lo(u.y); s[2] += f; q[2] = fmaf(f, f, q[2]);
            f = bl_hi(u.y); s[3] += f; q[3] = fmaf(f, f, q[3]);
            f = bl_lo(u.z); s[4] += f; q[4] = fmaf(f, f, q[4]);
            f = bl_hi(u.z); s[5] += f; q[5] = fmaf(f, f, q[5]);
            f = bl_lo(u.w); s[6] += f; q[6] = fmaf(f, f, q[6]);
            f = bl_hi(u.w); s[7] += f; q[7] = fmaf(f, f, q[7]);
        }
    }
    #pragma unroll
    for (int j = 0; j < 8; ++j) {
        s[j] += __shfl_xor(s[j], 8); q[j] += __shfl_xor(q[j], 8);
        s[j] += __shfl_xor(s[j], 16); q[j] += __shfl_xor(q[j], 16);
        s[j] += __shfl_xor(s[j], 32); q[j] += __shfl_xor(q[j], 32);
    }
    if (lane < 8) {
        int f = sl * 64 + c * 8;
        #pragma unroll
        for (int j = 0; j < 8; ++j) {
            atomicAdd(&stats[f + j], s[j]);
            atomicAdd(&stats[128 + f + j], q[j]);
        }
    }
}

__global__ void finalize_kernel(const float* __restrict__ stats, const float* __restrict__ gamma,
                                const float* __restrict__ beta, float* __restrict__ ac) {
    int f = threadIdx.x;
    float mean = stats[f] * (1.f / N_NODES);
    float var = stats[128 + f] * (1.f / N_NODES) - mean * mean;
    float a = gamma[f] * rsqrtf(var + BN_EPS);
    ac[f] = a;
    ac[128 + f] = fmaf(-mean, a, beta[f]);
}

// ---------------- final aggregation: 6 rows per vmem instruction + log_softmax ----------------
__global__ __launch_bounds__(64) void agg_lsm_kernel(const u32* __restrict__ hin,
                                                     const float* __restrict__ dinv,
                                                     const int* __restrict__ offs,
                                                     const int* __restrict__ csr,
                                                     const float* __restrict__ bias,
                                                     float* __restrict__ out) {
    const int i = blockIdx.x;
    const int l = threadIdx.x;
    int g = l / 10;
    const int c = l - g * 10;
    const bool act = g < 6;
    if (!act) g = 5;
    const float di = dinv[i];
    const int e0 = offs[i], e1 = offs[i + 1];
    float a[4] = {};
    int e = e0;
    for (; e + 12 <= e1; e += 12) {
        int sA = csr[e + g];
        int sB = csr[e + 6 + g];
        uint2 uA = *(const uint2*)(hin + (size_t)sA * 20 + c * 2);
        uint2 uB = *(const uint2*)(hin + (size_t)sB * 20 + c * 2);
        if (act) {
            a[0] += bl_lo(uA.x); a[1] += bl_hi(uA.x); a[2] += bl_lo(uA.y); a[3] += bl_hi(uA.y);
            a[0] += bl_lo(uB.x); a[1] += bl_hi(uB.x); a[2] += bl_lo(uB.y); a[3] += bl_hi(uB.y);
        }
    }
    if (e + 6 <= e1) {
        int s = csr[e + g];
        uint2 u = *(const uint2*)(hin + (size_t)s * 20 + c * 2);
        if (act) {
            a[0] += bl_lo(u.x); a[1] += bl_hi(u.x); a[2] += bl_lo(u.y); a[3] += bl_hi(u.y);
        }
        e += 6;
    }
    if (e < e1) {
        int idx = e + g;
        bool on = act && (idx < e1);
        if (on) {
            int s = csr[idx];
            uint2 u = *(const uint2*)(hin + (size_t)s * 20 + c * 2);
            a[0] += bl_lo(u.x); a[1] += bl_hi(u.x); a[2] += bl_lo(u.y); a[3] += bl_hi(u.y);
        }
    }
    #pragma unroll
    for (int j = 0; j < 4; ++j) {
        a[j] += __shfl(a[j], (l + 30) & 63);
        float t1 = __shfl(a[j], (l + 10) & 63);
        float t2 = __shfl(a[j], (l + 20) & 63);
        a[j] += t1 + t2;
    }
    float v0 = 0.f, v1 = 0.f, v2 = 0.f, v3 = 0.f;
    if (l < 10) {
        v0 = fmaf(a[0], di, bias[c * 4 + 0]);
        v1 = fmaf(a[1], di, bias[c * 4 + 1]);
        v2 = fmaf(a[2], di, bias[c * 4 + 2]);
        v3 = fmaf(a[3], di, bias[c * 4 + 3]);
    }
    float m = (l < 10) ? fmaxf(fmaxf(v0, v1), fmaxf(v2, v3)) : -INFINITY;
    #pragma unroll
    for (int o = 32; o >= 1; o >>= 1) m = fmaxf(m, __shfl_xor(m, o));
    float ex = (l < 10) ? (__expf(v0 - m) + __expf(v1 - m) + __expf(v2 - m) + __expf(v3 - m)) : 0.f;
    float sum = ex;
    #pragma unroll
    for (int o = 32; o >= 1; o >>= 1) sum += __shfl_xor(sum, o);
    float lse = m + __logf(sum);
    if (l < 10) {
        float4 r = make_float4(v0 - lse, v1 - lse, v2 - lse, v3 - lse);
        *((float4*)(out + (size_t)i * 40) + c) = r;
    }
}

extern "C" void kernel_launch(void* const* d_in, const int* in_sizes, int n_in,
                              void* d_out, int out_size, void* d_ws, size_t ws_size,
                              hipStream_t stream) {
    const float* x   = (const float*)d_in[0];
    const int*   ei  = (const int*)d_in[1];
    const float* W1  = (const float*)d_in[2];
    const float* b1  = (const float*)d_in[3];
    const float* g1  = (const float*)d_in[4];
    const float* be1 = (const float*)d_in[5];
    const float* W2  = (const float*)d_in[6];
    const float* b2  = (const float*)d_in[7];
    const float* g2  = (const float*)d_in[8];
    const float* be2 = (const float*)d_in[9];
    const float* W3  = (const float*)d_in[10];
    const float* b3  = (const float*)d_in[11];
    float* out = (float*)d_out;

    char* w = (char*)d_ws;
    size_t off = 0;
    auto take = [&](size_t bytes) {
        void* p = w + off;
        off = (off + bytes + 255) & ~(size_t)255;
        return p;
    };
    float* dinv   = (float*)take((size_t)N_NODES * 4);
    int*   offs   = (int*)take((size_t)(N_NODES + 1) * 4);
    int*   csr    = (int*)take((size_t)(N_EDGES + N_NODES) * 4);
    float* stats1 = (float*)take(256 * 4);
    float* stats2 = (float*)take(256 * 4);
    float* ac1    = (float*)take(256 * 4);
    float* ac2    = (float*)take(256 * 4);
    u16*   Wt1    = (u16*)take(128 * 128 * 2);
    u16*   Wt2    = (u16*)take(128 * 128 * 2);
    u16*   Wt3    = (u16*)take(48 * 128 * 2);
    u32*   bufA   = (u32*)take((size_t)N_NODES * 64 * 4);   // sliced bf16 [2][N][64]
    u32*   bufB   = (u32*)take((size_t)N_NODES * 64 * 4);   // sliced bf16 [2][N][64]

    u32*  ebuf     = (u32*)bufA;   // packed (dl<<17)|src, 6.4 MB
    int*  runstart = (int*)bufB;
    u32*  Y3       = (u32*)bufA;   // pre-scaled bf16 [N][40] layer-3 logits

    prep_w<<<4, 256, 0, stream>>>(W1, W2, W3, Wt1, Wt2, Wt3, stats1, stats2);
    binA_kernel<<<GBIN, 256, 0, stream>>>(ei, ebuf, runstart);
    binC_kernel<<<NBKT, 256, 0, stream>>>(ebuf, runstart, csr, offs, dinv);

    const int gm = (N_NODES + 63) / 64;        // 1563
    const int ga = 2 * N_NODES;                // 200000 (slice = blockIdx & 1)
    // layer 1
    mfma_gemm<false, false, 128, 0><<<gm, 256, 0, stream>>>(x, Wt1, nullptr, dinv, bufA);
    agg_kernel<<<ga, 64, 0, stream>>>(bufA, dinv, offs, csr, b1, bufB);
    stats_kernel<<<512, 256, 0, stream>>>(bufB, stats1);
    finalize_kernel<<<1, 128, 0, stream>>>(stats1, g1, be1, ac1);
    // layer 2
    mfma_gemm<true, true, 128, 0><<<gm, 256, 0, stream>>>(bufB, Wt2, ac1, dinv, bufA);
    agg_kernel<<<ga, 64, 0, stream>>>(bufA, dinv, offs, csr, b2, bufB);
    stats_kernel<<<512, 256, 0, stream>>>(bufB, stats2);
    finalize_kernel<<<1, 128, 0, stream>>>(stats2, g2, be2, ac2);
    // layer 3 (width 40, pre-scaled bf16 out)
    mfma_gemm<true, true, 48, 1><<<gm, 256, 0, stream>>>(bufB, Wt3, ac2, dinv, Y3);
    agg_lsm_kernel<<<N_NODES, 64, 0, stream>>>(Y3, dinv, offs, csr, b3, out);
}

// Round 13
// 345.049 us; speedup vs baseline: 2.2095x; 2.2095x over previous
//
#include <hip/hip_runtime.h>
#include <math.h>

#define N_NODES 100000
#define N_EDGES 1600000
#define NCLS 40
#define BN_EPS 1e-5f

// ---- bucketed CSR build parameters ----
#define BSPAN 256
#define NBKT 391
#define GBIN 256
#define CHUNK (N_EDGES / GBIN)
#define ECAP 5120

typedef unsigned int u32;
typedef unsigned short u16;
typedef __attribute__((ext_vector_type(8))) short bf16x8;
typedef __attribute__((ext_vector_type(4))) float f32x4;

__device__ inline float bl_lo(u32 u) { u32 x = u << 16; return __builtin_bit_cast(float, x); }
__device__ inline float bl_hi(u32 u) { u32 x = u & 0xFFFF0000u; return __builtin_bit_cast(float, x); }
__device__ inline u16 f2bl(float f) {  // RNE
    u32 x = __builtin_bit_cast(u32, f);
    return (u16)((x + 0x7FFFu + ((x >> 16) & 1u)) >> 16);
}
__device__ inline u32 pk2(float lo, float hi) { return (u32)f2bl(lo) | ((u32)f2bl(hi) << 16); }

// ---------------- Phase A: per-WG bucket binning (packed u32 pairs) ----------------
__global__ __launch_bounds__(256) void binA_kernel(const int* __restrict__ ei,
                                                   u32* __restrict__ ebuf,
                                                   int* __restrict__ runstart) {
    __shared__ int hist[NBKT];
    __shared__ int tmp[256];
    const int s = blockIdx.x, tid = threadIdx.x;
    const int e0 = s * CHUNK;

    for (int b = tid; b < NBKT; b += 256) hist[b] = 0;
    __syncthreads();
    for (int j = tid; j < CHUNK; j += 256) {
        int dst = ei[N_EDGES + e0 + j];
        atomicAdd(&hist[dst >> 8], 1);
    }
    __syncthreads();
    int i0 = 2 * tid, i1 = 2 * tid + 1;
    int a = (i0 < NBKT) ? hist[i0] : 0;
    int c = (i1 < NBKT) ? hist[i1] : 0;
    int ps = a + c;
    tmp[tid] = ps;
    __syncthreads();
    for (int o = 1; o < 256; o <<= 1) {
        int t = (tid >= o) ? tmp[tid - o] : 0;
        __syncthreads();
        tmp[tid] += t;
        __syncthreads();
    }
    int excl = tmp[tid] - ps;
    if (i0 < NBKT) hist[i0] = excl;
    if (i1 < NBKT) hist[i1] = excl + a;
    __syncthreads();
    for (int b = tid; b < NBKT; b += 256) runstart[b * GBIN + s] = hist[b];
    if (tid == 0) runstart[NBKT * GBIN + s] = CHUNK;
    __syncthreads();
    for (int j = tid; j < CHUNK; j += 256) {
        int src = ei[e0 + j];
        int dst = ei[N_EDGES + e0 + j];
        int p = atomicAdd(&hist[dst >> 8], 1);
        ebuf[e0 + p] = (u32)src | ((u32)(dst & 255) << 17);
    }
}

// ---------------- Phase C: per-bucket counting sort in LDS ----------------
__global__ __launch_bounds__(256) void binC_kernel(const u32* __restrict__ ebuf,
                                                   const int* __restrict__ runstart,
                                                   int* __restrict__ csr, int* __restrict__ offs,
                                                   float* __restrict__ dinv) {
    __shared__ int srcs[ECAP];
    __shared__ unsigned char dl8[ECAP];
    __shared__ int sorted[ECAP + BSPAN];
    __shared__ int nodecnt[BSPAN];
    __shared__ int cursor[BSPAN];
    __shared__ int tmp[256];
    __shared__ int sbase;
    const int b = blockIdx.x, tid = threadIdx.x;
    const int nb0 = b * BSPAN;
    const int nnod = min(BSPAN, N_NODES - nb0);

    int r0 = runstart[b * GBIN + tid];
    int r1 = runstart[(b + 1) * GBIN + tid];
    int len = r1 - r0;

    tmp[tid] = r0;
    __syncthreads();
    for (int o = 128; o >= 1; o >>= 1) {
        if (tid < o) tmp[tid] += tmp[tid + o];
        __syncthreads();
    }
    if (tid == 0) sbase = tmp[0] + nb0;
    __syncthreads();
    const int base = sbase;

    tmp[tid] = len;
    __syncthreads();
    for (int o = 1; o < 256; o <<= 1) {
        int t = (tid >= o) ? tmp[tid - o] : 0;
        __syncthreads();
        tmp[tid] += t;
        __syncthreads();
    }
    int myoff = tmp[tid] - len;
    int total_e = tmp[255];
    if (total_e > ECAP) total_e = ECAP;
    for (int n = tid; n < BSPAN; n += 256) nodecnt[n] = 0;
    __syncthreads();
    const u32* seg = ebuf + (size_t)tid * CHUNK + r0;
    for (int j = 0; j < len; ++j) {
        int idx = myoff + j;
        if (idx >= ECAP) break;
        u32 p = seg[j];
        srcs[idx] = (int)(p & 0x1FFFFu);
        int dl = (int)(p >> 17);
        dl8[idx] = (unsigned char)dl;
        atomicAdd(&nodecnt[dl], 1);
    }
    __syncthreads();
    int cnt = (tid < nnod) ? (nodecnt[tid] + 1) : 0;
    tmp[tid] = cnt;
    __syncthreads();
    for (int o = 1; o < 256; o <<= 1) {
        int t = (tid >= o) ? tmp[tid - o] : 0;
        __syncthreads();
        tmp[tid] += t;
        __syncthreads();
    }
    int noff = tmp[tid] - cnt;
    if (tid < nnod) {
        cursor[tid] = noff + 1;
        sorted[noff] = nb0 + tid;
        offs[nb0 + tid] = base + noff;
        dinv[nb0 + tid] = rsqrtf((float)(nodecnt[tid] + 1));
    }
    if (b == NBKT - 1 && tid == 0) offs[N_NODES] = N_EDGES + N_NODES;
    __syncthreads();
    for (int idx = tid; idx < total_e; idx += 256) {
        int dl = dl8[idx];
        int p = atomicAdd(&cursor[dl], 1);
        sorted[p] = srcs[idx];
    }
    __syncthreads();
    int tot = total_e + nnod;
    for (int idx = tid; idx < tot; idx += 256) csr[base + idx] = sorted[idx];
}

// ---------------- W prep: transpose + bf16 (+ stats zeroing in block 3) ----------------
__global__ void prep_w(const float* __restrict__ W1, const float* __restrict__ W2,
                       const float* __restrict__ W3, u16* __restrict__ Wt1,
                       u16* __restrict__ Wt2, u16* __restrict__ Wt3,
                       float* __restrict__ stats1, float* __restrict__ stats2) {
    int b = blockIdx.x, t = threadIdx.x;
    if (b == 0) {
        for (int idx = t; idx < 128 * 128; idx += 256) {
            int c = idx >> 7, k = idx & 127;
            Wt1[idx] = f2bl(W1[k * 128 + c]);
        }
    } else if (b == 1) {
        for (int idx = t; idx < 128 * 128; idx += 256) {
            int c = idx >> 7, k = idx & 127;
            Wt2[idx] = f2bl(W2[k * 128 + c]);
        }
    } else if (b == 2) {
        for (int idx = t; idx < 48 * 128; idx += 256) {
            int c = idx >> 7, k = idx & 127;
            Wt3[idx] = (c < NCLS) ? f2bl(W3[k * NCLS + c]) : (u16)0;
        }
    } else {
        stats1[t] = 0.f;
        stats2[t] = 0.f;
    }
}

// ---------------- MFMA GEMM: Y = dinv[row] * (fold(X[M x 128]) @ W[128 x BN]) ----------------
template <bool FOLD, bool IN_BF16, int BN, int OUTMODE>
__global__ __launch_bounds__(256) void mfma_gemm(const void* __restrict__ Xv,
                                                 const u16* __restrict__ Wt,
                                                 const float* __restrict__ ac,
                                                 const float* __restrict__ dinv,
                                                 void* __restrict__ Yv) {
    __shared__ __align__(16) u16 sX[64 * 128];
    __shared__ __align__(16) u16 sW[BN * 128];
    const int tid = threadIdx.x;
    const int row0 = blockIdx.x * 64;

    for (int ci = tid; ci < BN * 16; ci += 256) {
        int n = ci >> 4, ch = ci & 15;
        uint4 v = *(const uint4*)(Wt + n * 128 + ch * 8);
        *(uint4*)&sW[n * 128 + ((ch ^ (n & 7)) * 8)] = v;
    }
    {
        int r = tid >> 2;
        int gr = row0 + r;
        if (gr >= N_NODES) gr = N_NODES - 1;
        #pragma unroll
        for (int i = 0; i < 4; ++i) {
            int ch = (tid & 3) * 4 + i;
            int k0 = ch * 8;
            float xv[8];
            if (IN_BF16) {
                uint4 v = *((const uint4*)Xv + (size_t)gr * 16 + ch);
                xv[0] = bl_lo(v.x); xv[1] = bl_hi(v.x);
                xv[2] = bl_lo(v.y); xv[3] = bl_hi(v.y);
                xv[4] = bl_lo(v.z); xv[5] = bl_hi(v.z);
                xv[6] = bl_lo(v.w); xv[7] = bl_hi(v.w);
            } else {
                float4 p = *((const float4*)Xv + (size_t)gr * 32 + ch * 2);
                float4 q = *((const float4*)Xv + (size_t)gr * 32 + ch * 2 + 1);
                xv[0] = p.x; xv[1] = p.y; xv[2] = p.z; xv[3] = p.w;
                xv[4] = q.x; xv[5] = q.y; xv[6] = q.z; xv[7] = q.w;
            }
            if (FOLD) {
                #pragma unroll
                for (int j = 0; j < 8; ++j)
                    xv[j] = fmaxf(fmaf(xv[j], ac[k0 + j], ac[128 + k0 + j]), 0.f);
            }
            uint4 w;
            w.x = pk2(xv[0], xv[1]); w.y = pk2(xv[2], xv[3]);
            w.z = pk2(xv[4], xv[5]); w.w = pk2(xv[6], xv[7]);
            *(uint4*)&sX[r * 128 + ((ch ^ (r & 7)) * 8)] = w;
        }
    }
    __syncthreads();

    const int w = tid >> 6, l = tid & 63;
    const int g = l >> 4;
    const int lrow = w * 16 + (l & 15);
    bf16x8 afrag[4];
    #pragma unroll
    for (int kc = 0; kc < 4; ++kc) {
        int ch = kc * 4 + g;
        afrag[kc] = *(const bf16x8*)&sX[lrow * 128 + ((ch ^ (lrow & 7)) * 8)];
    }
    float sc[4];
    #pragma unroll
    for (int r = 0; r < 4; ++r) {
        int row = row0 + w * 16 + g * 4 + r;
        sc[r] = (row < N_NODES) ? dinv[row] : 0.f;
    }
    #pragma unroll
    for (int cg = 0; cg < BN / 16; ++cg) {
        const int n = cg * 16 + (l & 15);
        f32x4 acc = {0.f, 0.f, 0.f, 0.f};
        #pragma unroll
        for (int kc = 0; kc < 4; ++kc) {
            int ch = kc * 4 + g;
            bf16x8 bfrag = *(const bf16x8*)&sW[n * 128 + ((ch ^ (n & 7)) * 8)];
            acc = __builtin_amdgcn_mfma_f32_16x16x32_bf16(afrag[kc], bfrag, acc, 0, 0, 0);
        }
        #pragma unroll
        for (int r = 0; r < 4; ++r) {
            int row = row0 + w * 16 + g * 4 + r;
            if (row < N_NODES) {
                if (OUTMODE == 0) {
                    ((u16*)Yv)[(size_t)row * 128 + n] = f2bl(acc[r] * sc[r]);
                } else {
                    if (n < NCLS) ((u16*)Yv)[(size_t)row * NCLS + n] = f2bl(acc[r] * sc[r]);
                }
            }
        }
    }
}

// ---------------- aggregation: 4 rows per vmem instruction ----------------
// lane = g*16 + c : g = edge slot (0..3), c = 16B chunk of the 256B row.
__global__ __launch_bounds__(64) void agg_kernel(const u32* __restrict__ hin,
                                                 const float* __restrict__ dinv,
                                                 const int* __restrict__ offs,
                                                 const int* __restrict__ csr,
                                                 const float* __restrict__ bias,
                                                 u32* __restrict__ hout) {
    const int i = blockIdx.x;
    const int l = threadIdx.x;
    const int g = l >> 4, c = l & 15;
    const float di = dinv[i];
    const int e0 = offs[i], e1 = offs[i + 1];
    float a[8] = {};
    int e = e0;
    for (; e + 8 <= e1; e += 8) {
        int sA = csr[e + g];
        int sB = csr[e + 4 + g];
        uint4 uA = *(const uint4*)(hin + (size_t)sA * 64 + c * 4);
        uint4 uB = *(const uint4*)(hin + (size_t)sB * 64 + c * 4);
        a[0] += bl_lo(uA.x); a[1] += bl_hi(uA.x); a[2] += bl_lo(uA.y); a[3] += bl_hi(uA.y);
        a[4] += bl_lo(uA.z); a[5] += bl_hi(uA.z); a[6] += bl_lo(uA.w); a[7] += bl_hi(uA.w);
        a[0] += bl_lo(uB.x); a[1] += bl_hi(uB.x); a[2] += bl_lo(uB.y); a[3] += bl_hi(uB.y);
        a[4] += bl_lo(uB.z); a[5] += bl_hi(uB.z); a[6] += bl_lo(uB.w); a[7] += bl_hi(uB.w);
    }
    if (e + 4 <= e1) {
        int s = csr[e + g];
        uint4 u = *(const uint4*)(hin + (size_t)s * 64 + c * 4);
        a[0] += bl_lo(u.x); a[1] += bl_hi(u.x); a[2] += bl_lo(u.y); a[3] += bl_hi(u.y);
        a[4] += bl_lo(u.z); a[5] += bl_hi(u.z); a[6] += bl_lo(u.w); a[7] += bl_hi(u.w);
        e += 4;
    }
    if (e < e1) {  // tail: 1..3 edges, masked groups
        int idx = e + g;
        bool on = idx < e1;
        int s = csr[on ? idx : (e1 - 1)];
        uint4 u = *(const uint4*)(hin + (size_t)s * 64 + c * 4);
        if (on) {
            a[0] += bl_lo(u.x); a[1] += bl_hi(u.x); a[2] += bl_lo(u.y); a[3] += bl_hi(u.y);
            a[4] += bl_lo(u.z); a[5] += bl_hi(u.z); a[6] += bl_lo(u.w); a[7] += bl_hi(u.w);
        }
    }
    #pragma unroll
    for (int j = 0; j < 8; ++j) {
        a[j] += __shfl_xor(a[j], 16);
        a[j] += __shfl_xor(a[j], 32);
    }
    if (l < 16) {
        float4 b0 = *(const float4*)(bias + c * 8);
        float4 b1 = *(const float4*)(bias + c * 8 + 4);
        uint4 o;
        o.x = pk2(fmaf(a[0], di, b0.x), fmaf(a[1], di, b0.y));
        o.y = pk2(fmaf(a[2], di, b0.z), fmaf(a[3], di, b0.w));
        o.z = pk2(fmaf(a[4], di, b1.x), fmaf(a[5], di, b1.y));
        o.w = pk2(fmaf(a[6], di, b1.z), fmaf(a[7], di, b1.w));
        *(uint4*)(hout + (size_t)i * 64 + c * 4) = o;
    }
}

// ---------------- BN statistics: wide vectorized + hierarchical reduce ----------------
__global__ __launch_bounds__(256) void stats_kernel(const u32* __restrict__ h,
                                                    float* __restrict__ stats) {
    __shared__ float sm[4 * 256];
    const int tid = threadIdx.x;
    const int lane = tid & 63, wv = tid >> 6;
    const int wid = blockIdx.x * 4 + wv;
    const int nw = gridDim.x * 4;
    float s[8] = {}, q[8] = {};
    for (int quad = wid; quad < N_NODES / 4; quad += nw) {
        uint4 v = *(const uint4*)(h + (size_t)quad * 256 + lane * 4);
        float f;
        f = bl_lo(v.x); s[0] += f; q[0] = fmaf(f, f, q[0]);
        f = bl_hi(v.x); s[1] += f; q[1] = fmaf(f, f, q[1]);
        f = bl_lo(v.y); s[2] += f; q[2] = fmaf(f, f, q[2]);
        f = bl_hi(v.y); s[3] += f; q[3] = fmaf(f, f, q[3]);
        f = bl_lo(v.z); s[4] += f; q[4] = fmaf(f, f, q[4]);
        f = bl_hi(v.z); s[5] += f; q[5] = fmaf(f, f, q[5]);
        f = bl_lo(v.w); s[6] += f; q[6] = fmaf(f, f, q[6]);
        f = bl_hi(v.w); s[7] += f; q[7] = fmaf(f, f, q[7]);
    }
    #pragma unroll
    for (int j = 0; j < 8; ++j) {
        s[j] += __shfl_xor(s[j], 16); s[j] += __shfl_xor(s[j], 32);
        q[j] += __shfl_xor(q[j], 16); q[j] += __shfl_xor(q[j], 32);
    }
    if (lane < 16) {
        #pragma unroll
        for (int j = 0; j < 8; ++j) {
            sm[wv * 256 + 8 * lane + j] = s[j];
            sm[wv * 256 + 128 + 8 * lane + j] = q[j];
        }
    }
    __syncthreads();
    float v = sm[tid] + sm[256 + tid] + sm[512 + tid] + sm[768 + tid];
    atomicAdd(&stats[tid], v);
}

__global__ void finalize_kernel(const float* __restrict__ stats, const float* __restrict__ gamma,
                                const float* __restrict__ beta, float* __restrict__ ac) {
    int f = threadIdx.x;
    float mean = stats[f] * (1.f / N_NODES);
    float var = stats[128 + f] * (1.f / N_NODES) - mean * mean;
    float a = gamma[f] * rsqrtf(var + BN_EPS);
    ac[f] = a;
    ac[128 + f] = fmaf(-mean, a, beta[f]);
}

// ---------------- final aggregation: 6 rows per vmem instruction + log_softmax ----------------
// lane = g*10 + c : g = edge slot (0..5; lanes 60-63 inactive), c = 8B chunk of the 80B row.
__global__ __launch_bounds__(64) void agg_lsm_kernel(const u32* __restrict__ hin,
                                                     const float* __restrict__ dinv,
                                                     const int* __restrict__ offs,
                                                     const int* __restrict__ csr,
                                                     const float* __restrict__ bias,
                                                     float* __restrict__ out) {
    const int i = blockIdx.x;
    const int l = threadIdx.x;
    int g = l / 10;
    const int c = l - g * 10;
    const bool act = g < 6;
    if (!act) g = 5;
    const float di = dinv[i];
    const int e0 = offs[i], e1 = offs[i + 1];
    float a[4] = {};
    int e = e0;
    for (; e + 12 <= e1; e += 12) {
        int sA = csr[e + g];
        int sB = csr[e + 6 + g];
        uint2 uA = *(const uint2*)(hin + (size_t)sA * 20 + c * 2);
        uint2 uB = *(const uint2*)(hin + (size_t)sB * 20 + c * 2);
        if (act) {
            a[0] += bl_lo(uA.x); a[1] += bl_hi(uA.x); a[2] += bl_lo(uA.y); a[3] += bl_hi(uA.y);
            a[0] += bl_lo(uB.x); a[1] += bl_hi(uB.x); a[2] += bl_lo(uB.y); a[3] += bl_hi(uB.y);
        }
    }
    if (e + 6 <= e1) {
        int s = csr[e + g];
        uint2 u = *(const uint2*)(hin + (size_t)s * 20 + c * 2);
        if (act) {
            a[0] += bl_lo(u.x); a[1] += bl_hi(u.x); a[2] += bl_lo(u.y); a[3] += bl_hi(u.y);
        }
        e += 6;
    }
    if (e < e1) {
        int idx = e + g;
        bool on = act && (idx < e1);
        if (on) {
            int s = csr[idx];
            uint2 u = *(const uint2*)(hin + (size_t)s * 20 + c * 2);
            a[0] += bl_lo(u.x); a[1] += bl_hi(u.x); a[2] += bl_lo(u.y); a[3] += bl_hi(u.y);
        }
    }
    #pragma unroll
    for (int j = 0; j < 4; ++j) {
        a[j] += __shfl(a[j], (l + 30) & 63);
        float t1 = __shfl(a[j], (l + 10) & 63);
        float t2 = __shfl(a[j], (l + 20) & 63);
        a[j] += t1 + t2;
    }
    float v0 = 0.f, v1 = 0.f, v2 = 0.f, v3 = 0.f;
    if (l < 10) {
        v0 = fmaf(a[0], di, bias[c * 4 + 0]);
        v1 = fmaf(a[1], di, bias[c * 4 + 1]);
        v2 = fmaf(a[2], di, bias[c * 4 + 2]);
        v3 = fmaf(a[3], di, bias[c * 4 + 3]);
    }
    float m = (l < 10) ? fmaxf(fmaxf(v0, v1), fmaxf(v2, v3)) : -INFINITY;
    #pragma unroll
    for (int o = 32; o >= 1; o >>= 1) m = fmaxf(m, __shfl_xor(m, o));
    float ex = (l < 10) ? (__expf(v0 - m) + __expf(v1 - m) + __expf(v2 - m) + __expf(v3 - m)) : 0.f;
    float sum = ex;
    #pragma unroll
    for (int o = 32; o >= 1; o >>= 1) sum += __shfl_xor(sum, o);
    float lse = m + __logf(sum);
    if (l < 10) {
        float4 r = make_float4(v0 - lse, v1 - lse, v2 - lse, v3 - lse);
        *((float4*)(out + (size_t)i * 40) + c) = r;
    }
}

extern "C" void kernel_launch(void* const* d_in, const int* in_sizes, int n_in,
                              void* d_out, int out_size, void* d_ws, size_t ws_size,
                              hipStream_t stream) {
    const float* x   = (const float*)d_in[0];
    const int*   ei  = (const int*)d_in[1];
    const float* W1  = (const float*)d_in[2];
    const float* b1  = (const float*)d_in[3];
    const float* g1  = (const float*)d_in[4];
    const float* be1 = (const float*)d_in[5];
    const float* W2  = (const float*)d_in[6];
    const float* b2  = (const float*)d_in[7];
    const float* g2  = (const float*)d_in[8];
    const float* be2 = (const float*)d_in[9];
    const float* W3  = (const float*)d_in[10];
    const float* b3  = (const float*)d_in[11];
    float* out = (float*)d_out;

    char* w = (char*)d_ws;
    size_t off = 0;
    auto take = [&](size_t bytes) {
        void* p = w + off;
        off = (off + bytes + 255) & ~(size_t)255;
        return p;
    };
    float* dinv   = (float*)take((size_t)N_NODES * 4);
    int*   offs   = (int*)take((size_t)(N_NODES + 1) * 4);
    int*   csr    = (int*)take((size_t)(N_EDGES + N_NODES) * 4);
    float* stats1 = (float*)take(256 * 4);
    float* stats2 = (float*)take(256 * 4);
    float* ac1    = (float*)take(256 * 4);
    float* ac2    = (float*)take(256 * 4);
    u16*   Wt1    = (u16*)take(128 * 128 * 2);
    u16*   Wt2    = (u16*)take(128 * 128 * 2);
    u16*   Wt3    = (u16*)take(48 * 128 * 2);
    u32*   bufA   = (u32*)take((size_t)N_NODES * 64 * 4);
    u32*   bufB   = (u32*)take((size_t)N_NODES * 64 * 4);

    u32*  ebuf     = (u32*)bufA;   // packed (dl<<17)|src, 6.4 MB
    int*  runstart = (int*)bufB;
    u32*  Y3       = (u32*)bufA;   // pre-scaled bf16 [N][40] layer-3 logits

    prep_w<<<4, 256, 0, stream>>>(W1, W2, W3, Wt1, Wt2, Wt3, stats1, stats2);
    binA_kernel<<<GBIN, 256, 0, stream>>>(ei, ebuf, runstart);
    binC_kernel<<<NBKT, 256, 0, stream>>>(ebuf, runstart, csr, offs, dinv);

    const int gm = (N_NODES + 63) / 64;   // 1563
    // layer 1
    mfma_gemm<false, false, 128, 0><<<gm, 256, 0, stream>>>(x, Wt1, nullptr, dinv, bufA);
    agg_kernel<<<N_NODES, 64, 0, stream>>>(bufA, dinv, offs, csr, b1, bufB);
    stats_kernel<<<512, 256, 0, stream>>>(bufB, stats1);
    finalize_kernel<<<1, 128, 0, stream>>>(stats1, g1, be1, ac1);
    // layer 2
    mfma_gemm<true, true, 128, 0><<<gm, 256, 0, stream>>>(bufB, Wt2, ac1, dinv, bufA);
    agg_kernel<<<N_NODES, 64, 0, stream>>>(bufA, dinv, offs, csr, b2, bufB);
    stats_kernel<<<512, 256, 0, stream>>>(bufB, stats2);
    finalize_kernel<<<1, 128, 0, stream>>>(stats2, g2, be2, ac2);
    // layer 3 (width 40, pre-scaled bf16 out)
    mfma_gemm<true, true, 48, 1><<<gm, 256, 0, stream>>>(bufB, Wt3, ac2, dinv, Y3);
    agg_lsm_kernel<<<N_NODES, 64, 0, stream>>>(Y3, dinv, offs, csr, b3, out);
}